// Round 5
// baseline (290.393 us; speedup 1.0000x reference)
//
#include <hip/hip_runtime.h>
#include <hip/hip_bf16.h>

// AttentivePredictionFusion: B=8, T=2048, D=512, H=128. fp32 in, fp32 out.
// R13: attn occupancy was GRID-capped (512 blocks = 2 blocks/CU; R12 bought
// LDS/VGPR headroom that couldn't be used). Changes (attn only):
//  - d-chunk 128 -> grid 1024 blocks (bid&7=z XCD-pinned, (bid>>3)&31=q-tile,
//    bid>>8=d-chunk). QK dup 4x (34 GF) is cheap while latency-bound.
//  - Q-hoist: Q fragments in registers (loop-invariant, 32 VGPR), sQ deleted
//    (-16KB LDS, -8 b128 LDS reads/wave-iter). LDS 25.5KB.
//  - PV per wave: O[64][w*32..+32], oacc 64->32 VGPR (funds Q frags).
//  - __launch_bounds__(256,3): VGPR cap 168, est ~140, no spill (R10 lesson:
//    do NOT chase 128-cap/4-wave).
// Per wave-iter: QK 8 MFMA + 8 sK reads; PV 8 MFMA + 8 sP reads + 4 V global.

#define APF_B 8
#define APF_T 2048
#define APF_D 512
#define APF_H 128
#define APF_M (APF_B * APF_T)   // 16384
#define FA_SB 64                // attn s-tile per iteration

typedef unsigned short u16;
typedef __attribute__((ext_vector_type(8))) short short8;
typedef __attribute__((ext_vector_type(4))) float f32x4;
typedef __attribute__((ext_vector_type(16))) float f32x16;

static __device__ __forceinline__ u16 f2bf(float x) {
    union { float f; unsigned int u; } cv;
    cv.f = x;
    unsigned int u = cv.u + 0x7FFFu + ((cv.u >> 16) & 1u);  // RNE
    return (u16)(u >> 16);
}

// async global->LDS, 16 B per lane; LDS dest = wave-uniform base + lane*16
static __device__ __forceinline__ void load16_lds(const u16* g, u16* l) {
    __builtin_amdgcn_global_load_lds(
        (const __attribute__((address_space(1))) unsigned int*)g,
        (__attribute__((address_space(3))) unsigned int*)l,
        16, 0, 0);
}

static __device__ __forceinline__ f32x16 zero16() {
    f32x16 v;
#pragma unroll
    for (int i = 0; i < 16; ++i) v[i] = 0.f;
    return v;
}

// ---------------- prep kernel (cvt + weight transposes, one launch) --------

__global__ __launch_bounds__(256) void prep_all(
    const float* __restrict__ x,    u16* __restrict__ xb,
    const float* __restrict__ pred, u16* __restrict__ predb, long n4,
    const float* __restrict__ Wq, u16* __restrict__ WqT,
    const float* __restrict__ Wk, u16* __restrict__ WkT,
    const float* __restrict__ Wv, u16* __restrict__ WvT,
    const float* __restrict__ Wf, u16* __restrict__ WfT)
{
    const int bid = blockIdx.x;
    if (bid < 1024) {
        long i = bid * 256L + threadIdx.x;
        const long stride = 1024 * 256L;
        for (; i < 2 * n4; i += stride) {
            const float* in = (i < n4) ? x : pred;
            u16* out = (i < n4) ? xb : predb;
            const long j = (i < n4) ? i : (i - n4);
            const float4 v = ((const float4*)in)[j];
            ushort4 o;
            o.x = f2bf(v.x); o.y = f2bf(v.y); o.z = f2bf(v.z); o.w = f2bf(v.w);
            ((ushort4*)out)[j] = o;
        }
    } else {
        const long e = (bid - 1024) * 256L + threadIdx.x;
        if (e < 65536) {
            const long idx = e;              // Wq: K=512,N=128
            const long n = idx / 512, k = idx % 512;
            WqT[idx] = f2bf(Wq[k * 128 + n]);
        } else if (e < 131072) {
            const long idx = e - 65536;      // Wk
            const long n = idx / 512, k = idx % 512;
            WkT[idx] = f2bf(Wk[k * 128 + n]);
        } else if (e < 393216) {
            const long idx = e - 131072;     // Wv: K=512,N=512
            const long n = idx / 512, k = idx % 512;
            WvT[idx] = f2bf(Wv[k * 512 + n]);
        } else if (e < 917504) {
            const long idx = e - 393216;     // Wf: K=1024,N=512
            const long n = idx / 1024, k = idx % 1024;
            WfT[idx] = f2bf(Wf[k * 512 + n]);
        }
    }
}

// ---------------- MFMA GEMM (projections / fusion / vT) ----------------
// A: bf16 [M][K]; B: bf16 [N][K]. DUAL: 0 plain batched; 1 concat-A; 2 z-select.
// EPI: 0 bf16 store +bias; 2 fp32 sigmoid store +bias.
// BIASM: 0 bias indexed by n (output col); 1 bias indexed by m (output row).
// VBLK: 1 -> store blocked [m/32][n/8][m&31][n&7] (V-fragment-friendly).
// Double-buffered LDS: STAGE(t+1) issued before compute(t); one barrier/step.
template <int DUAL, int EPI, int BIASM, int VBLK>
__global__ __launch_bounds__(256) void mfma_gemm(
    const u16* __restrict__ Ap, const u16* __restrict__ A2p, long lda,
    const u16* __restrict__ Bp, const u16* __restrict__ Bp2, long ldb,
    const float* __restrict__ biasp, const float* __restrict__ bias2,
    void* __restrict__ Cp, void* __restrict__ Cp2, long ldc, int K,
    long sA, long sB, long sC)
{
    __shared__ u16 smA[2][128 * 32];
    __shared__ u16 smB[2][128 * 32];

    const int tid  = threadIdx.x;
    const int lane = tid & 63;
    const int wid  = tid >> 6;
    const int wr   = wid >> 1;
    const int wc   = wid & 1;

    const long row0 = (long)blockIdx.y * 128;
    const long col0 = (long)blockIdx.x * 128;
    const long z    = blockIdx.z;

    const u16* Abase = (DUAL == 2) ? (z ? A2p : Ap) : (Ap + z * sA);
    const u16* Bbase = (DUAL == 2) ? (z ? Bp2 : Bp) : (Bp + z * sB);

    f32x4 acc[4][4];
#pragma unroll
    for (int i = 0; i < 4; ++i)
#pragma unroll
        for (int j = 0; j < 4; ++j)
            acc[i][j] = (f32x4){0.f, 0.f, 0.f, 0.f};

    const int lrow = (lane >> 4) * 4;
    const int lcol = lane & 15;
    const int q8   = (lane >> 4) * 8;

    auto stage = [&](int buf, int kb) {
#pragma unroll
        for (int rep = 0; rep < 2; ++rep) {
            const int c  = tid + rep * 256;
            const int r  = c >> 2;
            const int kc = (c & 3) * 8;
            const int wbase = (wid * 64 + rep * 256) * 8;
            const u16* ga;
            if (DUAL == 1 && (kb + kc) >= APF_D) {
                ga = A2p + (row0 + r) * lda + (kb + kc - APF_D);
            } else {
                ga = Abase + (row0 + r) * lda + (kb + kc);
            }
            load16_lds(ga, &smA[buf][wbase]);
            const u16* gb = Bbase + (col0 + r) * ldb + (kb + kc);
            load16_lds(gb, &smB[buf][wbase]);
        }
    };

    const int NT = K / 32;
    stage(0, 0);
    __syncthreads();            // vmcnt(0)+barrier: buf0 ready
    int cur = 0;

    for (int t = 0; t < NT; ++t) {
        if (t + 1 < NT) stage(cur ^ 1, (t + 1) * 32);   // loads fly under MFMA

        short8 av[4], bv4[4];
#pragma unroll
        for (int ti = 0; ti < 4; ++ti)
            av[ti] = *(const short8*)&smA[cur][(wr * 64 + ti * 16 + lcol) * 32 + q8];
#pragma unroll
        for (int tj = 0; tj < 4; ++tj)
            bv4[tj] = *(const short8*)&smB[cur][(wc * 64 + tj * 16 + lcol) * 32 + q8];

#pragma unroll
        for (int ti = 0; ti < 4; ++ti)
#pragma unroll
            for (int tj = 0; tj < 4; ++tj)
                acc[ti][tj] = __builtin_amdgcn_mfma_f32_16x16x32_bf16(
                    av[ti], bv4[tj], acc[ti][tj], 0, 0, 0);

        __syncthreads();        // drains next-tile DMA + read/overwrite fence
        cur ^= 1;
    }

    const float* bias = (DUAL == 2 && z) ? bias2 : biasp;

#pragma unroll
    for (int ti = 0; ti < 4; ++ti) {
        const long m0t = row0 + wr * 64 + ti * 16 + lrow;
#pragma unroll
        for (int tj = 0; tj < 4; ++tj) {
            const long n = col0 + wc * 64 + tj * 16 + lcol;
            const float bn = (BIASM == 0 && bias != nullptr) ? bias[n] : 0.f;
            if (EPI == 0) {
                u16* C = (u16*)((DUAL == 2 && z) ? Cp2 : Cp) + ((DUAL == 2) ? 0 : z * sC);
#pragma unroll
                for (int r = 0; r < 4; ++r) {
                    const long m = m0t + r;
                    const float bm = (BIASM == 1) ? bias[m] : bn;
                    long idx;
                    if (VBLK) {
                        idx = ((((m >> 5) * 256) + (n >> 3)) << 8) +
                              ((m & 31) << 3) + (n & 7);
                    } else {
                        idx = m * ldc + n;
                    }
                    C[idx] = f2bf(acc[ti][tj][r] + bm);
                }
            } else {
                float* C = (float*)Cp;
#pragma unroll
                for (int r = 0; r < 4; ++r) {
                    const float val = acc[ti][tj][r] + bn;
                    C[(m0t + r) * ldc + n] = 1.0f / (1.0f + expf(-val));
                }
            }
        }
    }
}

// ---------------- fused attention ----------------
// Grid 1024 blocks (linear). bid&7 = batch z (XCD L2 locality); (bid>>3)&31 =
// Q-tile (64 rows); bid>>8 = d-chunk (128 cols). 256 threads = 4 waves.
// s-block 64, 32 iters. Q fragments hoisted to registers (loop-invariant).
// Per iter:
//   QK: wave w computes S[qb*32..+32][sb*32..+32] (qb=w>>1, sb=w&1):
//       8 MFMA 32x32x16, 8 sK b128 reads (Q from regs). [bar]
//   issue K(kt+1) DMA (pre-swizzled src -> linear sK); V (4 loads, blocked
//   layout, contiguous 1KB/wave-instr) global->reg; exp + rowsum + sP. [bar]
//   PV: wave w computes O[0:64][w*32..+32]: 8 MFMA, 8 sP reads.
// LDS 25.5KB; __launch_bounds__(256,3) -> 3 blocks/CU (12 waves).
__global__ __launch_bounds__(256, 3) void attn_fused(
    const u16* __restrict__ qg, const u16* __restrict__ kg,
    const u16* __restrict__ vTg, u16* __restrict__ attg)
{
    __shared__ u16 sK[64 * 128];     // 16 KB
    __shared__ u16 sP[64 * 64];      // 8 KB
    __shared__ float sRS[192];       // partials [4w][32] + inv [64]

    const int tid  = threadIdx.x;
    const int lane = tid & 63;
    const int w    = tid >> 6;       // 0..3
    const int l31  = lane & 31;
    const int hi   = lane >> 5;      // 0..1
    const int qb   = w >> 1;         // QK q-block
    const int sb   = w & 1;          // QK s-block

    const int  bid = blockIdx.x;
    const long z   = bid & 7;
    const int  r   = bid >> 3;
    const long q0  = (long)(r & 31) * 64;
    const long d0  = (long)(r >> 5) * 128;

    const u16* kbase0 = kg + z * (long)APF_T * APF_H;

    // prologue: K tile 0 via DMA (pre-swizzled source, linear LDS)
#pragma unroll
    for (int rep = 0; rep < 4; ++rep) {
        const int c    = tid + rep * 256;     // 0..1023
        const int row  = c >> 4;
        const int col8 = (c & 15) * 8;
        load16_lds(kbase0 + row * APF_H + (col8 ^ ((row & 15) << 3)), &sK[c * 8]);
    }

    // Q fragments: loop-invariant, straight from global (rows qb*32+l31)
    short8 qf[8];
    {
        const u16* qsrc = qg + (z * APF_T + q0 + qb * 32 + l31) * APF_H;
#pragma unroll
        for (int ks = 0; ks < 8; ++ks)
            qf[ks] = *(const short8*)(qsrc + ks * 16 + hi * 8);
    }
    __syncthreads();   // drains vmcnt: sK ready

    f32x16 oacc[2];
    oacc[0] = zero16(); oacc[1] = zero16();
    f32x16 rsacc = zero16();

    // blocked vT base for this wave: [z][dblk][s8][d&31][s&7]; dblk = one
    // 32-wide d-block per wave
    const long dblk0 = (d0 >> 5) + w;
    const u16* vzb = vTg + z * 1048576L + dblk0 * 65536L + (long)l31 * 8;

    const int krow = sb * 32 + l31;
    const int pcol = sb * 32 + l31;

    for (int kt = 0; kt < APF_T / FA_SB; ++kt) {
        // QK^T: S[qb*32..+32][sb*32..+32], h=128 -> 8 k-steps, 8 MFMA
        f32x16 sacc = zero16();
#pragma unroll
        for (int ks = 0; ks < 8; ++ks) {
            const int colk = ks * 16 + hi * 8;
            const short8 bv = *(const short8*)&sK[krow * 128 + (colk ^ ((krow & 15) << 3))];
            sacc = __builtin_amdgcn_mfma_f32_32x32x16_bf16(qf[ks], bv, sacc, 0, 0, 0);
        }
        __syncthreads();   // all waves done with sK(kt) and sP(kt-1)

        // issue next K tile DMA (completes by the sP barrier below)
        if (kt + 1 < APF_T / FA_SB) {
            const u16* ksrc = kbase0 + (long)(kt + 1) * FA_SB * APF_H;
#pragma unroll
            for (int rep = 0; rep < 4; ++rep) {
                const int c    = tid + rep * 256;
                const int row  = c >> 4;
                const int col8 = (c & 15) * 8;
                load16_lds(ksrc + row * APF_H + (col8 ^ ((row & 15) << 3)), &sK[c * 8]);
            }
        }

        // V prefetch (blocked layout: contiguous 1KB per instr), ks 0..3
        const long sbase = (long)kt * 8 + hi;
        short8 vf[4];
#pragma unroll
        for (int ks = 0; ks < 4; ++ks)
            vf[ks] = *(const short8*)(vzb + (sbase + ks * 2) * 256);

        // exp + rowsum accum + P -> sP (swizzled; C-layout -> A-layout hop)
#pragma unroll
        for (int rg = 0; rg < 16; ++rg) {
            const float e = __expf(sacc[rg]);
            rsacc[rg] += e;
            const int prow = qb * 32 + (rg & 3) + 8 * (rg >> 2) + 4 * hi;
            sP[prow * 64 + (pcol ^ ((prow & 7) << 3))] = f2bf(e);
        }
        __syncthreads();   // sP visible; vmcnt drained (K DMA + vf complete)

        // PV: O[0:64][w*32..+32] += P @ V^T  (8 MFMA, 8 sP reads)
#pragma unroll
        for (int ks = 0; ks < 4; ++ks) {
            const int colk = ks * 16 + hi * 8;
            short8 pa[2];
#pragma unroll
            for (int qt = 0; qt < 2; ++qt) {
                const int prow = qt * 32 + l31;
                pa[qt] = *(const short8*)&sP[prow * 64 + (colk ^ ((prow & 7) << 3))];
            }
#pragma unroll
            for (int qt = 0; qt < 2; ++qt)
                oacc[qt] = __builtin_amdgcn_mfma_f32_32x32x16_bf16(
                    pa[qt], vf[ks], oacc[qt], 0, 0, 0);
        }
    }

    // rowsum: reduce over the 32 s-cols (l31), publish per-wave partials
#pragma unroll
    for (int rg = 0; rg < 16; ++rg) {
        float s = rsacc[rg];
        s += __shfl_xor(s, 1);
        s += __shfl_xor(s, 2);
        s += __shfl_xor(s, 4);
        s += __shfl_xor(s, 8);
        s += __shfl_xor(s, 16);
        rsacc[rg] = s;
    }
    if (l31 == 0) {
#pragma unroll
        for (int rg = 0; rg < 16; ++rg) {
            const int row = (rg & 3) + 8 * (rg >> 2) + 4 * hi;   // 0..31
            sRS[w * 32 + row] = rsacc[rg];
        }
    }
    __syncthreads();
    if (tid < 64) {
        const int qb2 = tid >> 5, r2 = tid & 31;
        sRS[128 + tid] = 1.0f / (sRS[(qb2 * 2 + 0) * 32 + r2] +
                                 sRS[(qb2 * 2 + 1) * 32 + r2]);
    }
    __syncthreads();

    // store: 64 q rows x own 32 d cols
    const long rowg0 = z * APF_T + q0;
    const long colg  = d0 + (long)w * 32 + l31;
#pragma unroll
    for (int qt = 0; qt < 2; ++qt)
#pragma unroll
        for (int rg = 0; rg < 16; ++rg) {
            const int row = qt * 32 + (rg & 3) + 8 * (rg >> 2) + 4 * hi;
            attg[(rowg0 + row) * APF_D + colg] =
                f2bf(oacc[qt][rg] * sRS[128 + row]);
        }
}

extern "C" void kernel_launch(void* const* d_in, const int* in_sizes, int n_in,
                              void* d_out, int out_size, void* d_ws, size_t ws_size,
                              hipStream_t stream)
{
    (void)in_sizes; (void)n_in; (void)out_size; (void)ws_size;

    const float* x    = (const float*)d_in[0];
    const float* pred = (const float*)d_in[1];
    const float* Wq   = (const float*)d_in[2];
    const float* bq   = (const float*)d_in[3];
    const float* Wk   = (const float*)d_in[4];
    const float* bk   = (const float*)d_in[5];
    const float* Wv   = (const float*)d_in[6];
    const float* bv   = (const float*)d_in[7];
    const float* Wf   = (const float*)d_in[8];
    const float* bfu  = (const float*)d_in[9];

    // Workspace (u16), ~80 MB
    u16* wsp   = (u16*)d_ws;
    u16* xb    = wsp;                                  // [16384][512]
    u16* predb = xb    + (long)APF_M * APF_D;          // [16384][512]
    u16* qb    = predb + (long)APF_M * APF_D;          // [16384][128]
    u16* kbuf  = qb    + (long)APF_M * APF_H;          // [16384][128]
    u16* vTb   = kbuf  + (long)APF_M * APF_H;          // [8][16][256][32][8] blocked
    u16* attb  = vTb   + (long)APF_M * APF_D;          // [16384][512]
    u16* WqT   = attb  + (long)APF_M * APF_D;          // [128][512]
    u16* WkT   = WqT   + (long)APF_H * APF_D;          // [128][512]
    u16* WvT   = WkT   + (long)APF_H * APF_D;          // [512][512]
    u16* WfT   = WvT   + (long)APF_D * APF_D;          // [512][1024]

    const dim3 thr(256);
    const long nBTD4 = (long)APF_M * APF_D / 4;

    prep_all<<<dim3(1024 + 3584), thr, 0, stream>>>(
        x, xb, pred, predb, nBTD4, Wq, WqT, Wk, WkT, Wv, WvT, Wf, WfT);

    // q = pred@Wq+bq (z=0), k = x@Wk+bk (z=1)
    mfma_gemm<2, 0, 0, 0><<<dim3(1, 128, 2), thr, 0, stream>>>(
        predb, xb, APF_D, WqT, WkT, APF_D, bq, bk, qb, kbuf, APF_H, APF_D,
        0, 0, 0);

    // vT[z] = WvT @ xb[z]^T + bv, stored BLOCKED [d/32][s/8][d&31][s&7]
    mfma_gemm<0, 0, 1, 1><<<dim3(16, 4, 8), thr, 0, stream>>>(
        WvT, nullptr, APF_D, xb, nullptr, APF_D, bv, nullptr, vTb, nullptr,
        APF_T, APF_D, 0, (long)APF_T * APF_D, (long)APF_D * APF_T);

    // fused attention: att = softmax(q k^T) v   (one kernel, no scores buffer)
    attn_fused<<<dim3(1024), thr, 0, stream>>>(qb, kbuf, vTb, attb);

    // out = sigmoid([pred|att] @ Wf + bf) -> fp32 d_out
    mfma_gemm<1, 2, 0, 0><<<dim3(4, 128, 1), thr, 0, stream>>>(
        predb, attb, APF_D, WfT, nullptr, 2 * APF_D, bfu, nullptr, d_out, nullptr,
        APF_D, 2 * APF_D, 0, 0, 0);
}

// Round 6
// 253.969 us; speedup vs baseline: 1.1434x; 1.1434x over previous
//
#include <hip/hip_runtime.h>
#include <hip/hip_bf16.h>

// AttentivePredictionFusion: B=8, T=2048, D=512, H=128. fp32 in, fp32 out.
// R14:
//  - attn_fused reverted verbatim to R12 (75.9us best; R13's d-chunk-128
//    split doubled QK work -> 106us. Lesson: at MfmaUtil>=25%, duplication
//    isn't free).
//  - xb/predb bf16 copies DELETED: fp32->bf16 conversion fused into GEMM
//    staging (reg-stage float4x2 -> f2bf -> ds_write_b128). prep is now
//    weights-only (~3.5MB).
//  - qk-proj (256 blk) + vT (512 blk) merged into ONE 768-block launch
//    (mid_gemms): 3 blocks/CU instead of two serial 1-2 blk/CU launches.
//  - gemm_body: one-barrier dbuf; bf16 operands via global_load_lds (issued
//    after bar), fp32 operands reg-staged (loads before bar, writes after
//    compute); both drained by the single syncthreads per K-step.

#define APF_B 8
#define APF_T 2048
#define APF_D 512
#define APF_H 128
#define APF_M (APF_B * APF_T)   // 16384
#define FA_SB 128               // attn s-tile per iteration

typedef unsigned short u16;
typedef __attribute__((ext_vector_type(8))) short short8;
typedef __attribute__((ext_vector_type(4))) float f32x4;
typedef __attribute__((ext_vector_type(16))) float f32x16;

static __device__ __forceinline__ u16 f2bf(float x) {
    union { float f; unsigned int u; } cv;
    cv.f = x;
    unsigned int u = cv.u + 0x7FFFu + ((cv.u >> 16) & 1u);  // RNE
    return (u16)(u >> 16);
}

// async global->LDS, 16 B per lane; LDS dest = wave-uniform base + lane*16
static __device__ __forceinline__ void load16_lds(const u16* g, u16* l) {
    __builtin_amdgcn_global_load_lds(
        (const __attribute__((address_space(1))) unsigned int*)g,
        (__attribute__((address_space(3))) unsigned int*)l,
        16, 0, 0);
}

static __device__ __forceinline__ f32x16 zero16() {
    f32x16 v;
#pragma unroll
    for (int i = 0; i < 16; ++i) v[i] = 0.f;
    return v;
}

// ---------------- prep kernel (weight transposes only) ----------------

__global__ __launch_bounds__(256) void prep_w(
    const float* __restrict__ Wq, u16* __restrict__ WqT,
    const float* __restrict__ Wk, u16* __restrict__ WkT,
    const float* __restrict__ Wv, u16* __restrict__ WvT,
    const float* __restrict__ Wf, u16* __restrict__ WfT)
{
    const long e = blockIdx.x * 256L + threadIdx.x;
    if (e < 65536) {
        const long idx = e;              // Wq: K=512,N=128
        const long n = idx / 512, k = idx % 512;
        WqT[idx] = f2bf(Wq[k * 128 + n]);
    } else if (e < 131072) {
        const long idx = e - 65536;      // Wk
        const long n = idx / 512, k = idx % 512;
        WkT[idx] = f2bf(Wk[k * 128 + n]);
    } else if (e < 393216) {
        const long idx = e - 131072;     // Wv: K=512,N=512
        const long n = idx / 512, k = idx % 512;
        WvT[idx] = f2bf(Wv[k * 512 + n]);
    } else if (e < 917504) {
        const long idx = e - 393216;     // Wf: K=1024,N=512
        const long n = idx / 1024, k = idx % 1024;
        WfT[idx] = f2bf(Wf[k * 512 + n]);
    }
}

// ---------------- GEMM body (device function) ----------------
// C[128][128] tile = A[M][K] @ B[N][K]^T + bias.
// ADT: 0 = A bf16 (DMA), 1 = A fp32 (reg-stage+cvt), 2 = concat fp32|bf16
//      (k<512 from fp32 Ap, k>=512 from bf16 A2p).
// BDT: 0 = B bf16 (DMA), 1 = B fp32 (reg-stage+cvt).
// EPI: 0 bf16 store +bias; 2 fp32 sigmoid store +bias.
// BIASM: 0 bias[n]; 1 bias[m].   VBLK: 1 -> blocked [m/32][n/8][m&31][n&7].
template <int ADT, int BDT, int EPI, int BIASM, int VBLK>
static __device__ __forceinline__ void gemm_body(
    u16 (&smA)[2][4096], u16 (&smB)[2][4096],
    const void* Ap, const void* A2p, long lda,
    const void* Bp, long ldb,
    const float* bias, void* Cp, long ldc, int K,
    long row0, long col0)
{
    const int tid  = threadIdx.x;
    const int lane = tid & 63;
    const int wid  = tid >> 6;
    const int wr   = wid >> 1;
    const int wc   = wid & 1;

    f32x4 acc[4][4];
#pragma unroll
    for (int i = 0; i < 4; ++i)
#pragma unroll
        for (int j = 0; j < 4; ++j)
            acc[i][j] = (f32x4){0.f, 0.f, 0.f, 0.f};

    const int lrow = (lane >> 4) * 4;
    const int lcol = lane & 15;
    const int q8   = (lane >> 4) * 8;

    float4 ra[2][2], rb[2][2];

    auto loadA = [&](int kb) {
        if (ADT == 1 || (ADT == 2 && kb < APF_D)) {
            const float* Af = (const float*)Ap;
#pragma unroll
            for (int rep = 0; rep < 2; ++rep) {
                const int c = tid + rep * 256;
                const int rr = c >> 2, kc = (c & 3) * 8;
                const float* ga = Af + (row0 + rr) * lda + kb + kc;
                ra[rep][0] = *(const float4*)ga;
                ra[rep][1] = *(const float4*)(ga + 4);
            }
        }
    };
    auto loadB = [&](int kb) {
        if (BDT == 1) {
            const float* Bf = (const float*)Bp;
#pragma unroll
            for (int rep = 0; rep < 2; ++rep) {
                const int c = tid + rep * 256;
                const int rr = c >> 2, kc = (c & 3) * 8;
                const float* gb = Bf + (col0 + rr) * ldb + kb + kc;
                rb[rep][0] = *(const float4*)gb;
                rb[rep][1] = *(const float4*)(gb + 4);
            }
        }
    };
    auto dmaA = [&](int buf, int kb) {
        if (ADT == 0 || (ADT == 2 && kb >= APF_D)) {
            const u16* Ab = (ADT == 2) ? (const u16*)A2p : (const u16*)Ap;
            const int kk = (ADT == 2) ? kb - APF_D : kb;
            const long ld = (ADT == 2) ? APF_D : lda;
#pragma unroll
            for (int rep = 0; rep < 2; ++rep) {
                const int c = tid + rep * 256;
                const int rr = c >> 2, kc = (c & 3) * 8;
                const int wbase = (wid * 64 + rep * 256) * 8;
                load16_lds(Ab + (row0 + rr) * ld + kk + kc, &smA[buf][wbase]);
            }
        }
    };
    auto dmaB = [&](int buf, int kb) {
        if (BDT == 0) {
            const u16* Bb = (const u16*)Bp;
#pragma unroll
            for (int rep = 0; rep < 2; ++rep) {
                const int c = tid + rep * 256;
                const int rr = c >> 2, kc = (c & 3) * 8;
                const int wbase = (wid * 64 + rep * 256) * 8;
                load16_lds(Bb + (col0 + rr) * ldb + kb + kc, &smB[buf][wbase]);
            }
        }
    };
    auto cvt8 = [&](const float4& a, const float4& b) {
        short8 v;
        v[0] = (short)f2bf(a.x); v[1] = (short)f2bf(a.y);
        v[2] = (short)f2bf(a.z); v[3] = (short)f2bf(a.w);
        v[4] = (short)f2bf(b.x); v[5] = (short)f2bf(b.y);
        v[6] = (short)f2bf(b.z); v[7] = (short)f2bf(b.w);
        return v;
    };
    auto writeA = [&](int buf, int kb) {
        if (ADT == 1 || (ADT == 2 && kb < APF_D)) {
#pragma unroll
            for (int rep = 0; rep < 2; ++rep) {
                const int c = tid + rep * 256;
                *(short8*)&smA[buf][c * 8] = cvt8(ra[rep][0], ra[rep][1]);
            }
        }
    };
    auto writeB = [&](int buf, int kb) {
        if (BDT == 1) {
#pragma unroll
            for (int rep = 0; rep < 2; ++rep) {
                const int c = tid + rep * 256;
                *(short8*)&smB[buf][c * 8] = cvt8(rb[rep][0], rb[rep][1]);
            }
        }
    };

    const int NT = K / 32;
    // prologue: tile 0
    loadA(0); loadB(0);
    writeA(0, 0); writeB(0, 0);
    dmaA(0, 0); dmaB(0, 0);

    int cur = 0;
    for (int t = 0; t < NT; ++t) {
        const int kb2 = (t + 1) * 32;
        if (t + 1 < NT) { loadA(kb2); loadB(kb2); }   // fp32 reg loads (no LDS)
        __syncthreads();                               // drains DMA+writes of cur
        if (t + 1 < NT) { dmaA(cur ^ 1, kb2); dmaB(cur ^ 1, kb2); }

        short8 av[4], bv4[4];
#pragma unroll
        for (int ti = 0; ti < 4; ++ti)
            av[ti] = *(const short8*)&smA[cur][(wr * 64 + ti * 16 + lcol) * 32 + q8];
#pragma unroll
        for (int tj = 0; tj < 4; ++tj)
            bv4[tj] = *(const short8*)&smB[cur][(wc * 64 + tj * 16 + lcol) * 32 + q8];

#pragma unroll
        for (int ti = 0; ti < 4; ++ti)
#pragma unroll
            for (int tj = 0; tj < 4; ++tj)
                acc[ti][tj] = __builtin_amdgcn_mfma_f32_16x16x32_bf16(
                    av[ti], bv4[tj], acc[ti][tj], 0, 0, 0);

        if (t + 1 < NT) { writeA(cur ^ 1, kb2); writeB(cur ^ 1, kb2); }
        cur ^= 1;
    }

#pragma unroll
    for (int ti = 0; ti < 4; ++ti) {
        const long m0t = row0 + wr * 64 + ti * 16 + lrow;
#pragma unroll
        for (int tj = 0; tj < 4; ++tj) {
            const long n = col0 + wc * 64 + tj * 16 + lcol;
            const float bn = (BIASM == 0) ? bias[n] : 0.f;
            if (EPI == 0) {
                u16* C = (u16*)Cp;
#pragma unroll
                for (int r = 0; r < 4; ++r) {
                    const long m = m0t + r;
                    const float bm = (BIASM == 1) ? bias[m] : bn;
                    long idx;
                    if (VBLK) {
                        idx = ((((m >> 5) * 256) + (n >> 3)) << 8) +
                              ((m & 31) << 3) + (n & 7);
                    } else {
                        idx = m * ldc + n;
                    }
                    C[idx] = f2bf(acc[ti][tj][r] + bm);
                }
            } else {
                float* C = (float*)Cp;
#pragma unroll
                for (int r = 0; r < 4; ++r) {
                    const float val = acc[ti][tj][r] + bn;
                    C[(m0t + r) * ldc + n] = 1.0f / (1.0f + expf(-val));
                }
            }
        }
    }
}

// ---------------- mid GEMMs: q/k projections + vT, one 768-block launch ----
// bid<256: qk. zz=bid>>7 (0:q from pred/WqT, 1:k from x/WkT), by=bid&127.
//   A fp32 [16384][512], B bf16 [128][512], C bf16 [16384][128].
// bid>=256: vT. t=bid-256; zz=t>>6; bx=(t&63)&15; by=(t&63)>>4.
//   A=WvT bf16 [512][512], B=x[zz] fp32 [2048][512], C blocked, bias on m.
__global__ __launch_bounds__(256, 3) void mid_gemms(
    const float* __restrict__ x, const float* __restrict__ pred,
    const u16* __restrict__ WqT, const u16* __restrict__ WkT,
    const u16* __restrict__ WvT,
    const float* __restrict__ bq, const float* __restrict__ bk,
    const float* __restrict__ bv,
    u16* __restrict__ qb, u16* __restrict__ kbuf, u16* __restrict__ vTb)
{
    __shared__ u16 smA[2][4096];
    __shared__ u16 smB[2][4096];

    const int bid = blockIdx.x;
    if (bid < 256) {
        const int zz = bid >> 7, by = bid & 127;
        gemm_body<1, 0, 0, 0, 0>(smA, smB,
            zz ? (const void*)x : (const void*)pred, nullptr, APF_D,
            zz ? WkT : WqT, APF_D,
            zz ? bk : bq, zz ? (void*)kbuf : (void*)qb, APF_H, APF_D,
            (long)by * 128, 0);
    } else {
        const int t = bid - 256;
        const int zz = t >> 6, rem = t & 63;
        const int bx = rem & 15, by = rem >> 4;
        gemm_body<0, 1, 0, 1, 1>(smA, smB,
            WvT, nullptr, APF_D,
            (const void*)(x + (long)zz * APF_T * APF_D), APF_D,
            bv, (void*)(vTb + (long)zz * 1048576L), APF_T, APF_D,
            (long)by * 128, (long)bx * 128);
    }
}

// ---------------- fusion GEMM: out = sigmoid([pred|att] @ Wf + bf) --------
__global__ __launch_bounds__(256, 2) void fusion_gemm(
    const float* __restrict__ pred, const u16* __restrict__ attb,
    const u16* __restrict__ WfT, const float* __restrict__ bfu,
    float* __restrict__ out)
{
    __shared__ u16 smA[2][4096];
    __shared__ u16 smB[2][4096];
    gemm_body<2, 0, 2, 0, 0>(smA, smB,
        (const void*)pred, (const void*)attb, APF_D,
        WfT, 2 * APF_D,
        bfu, (void*)out, APF_D, 2 * APF_D,
        (long)blockIdx.y * 128, (long)blockIdx.x * 128);
}

// ---------------- fused attention (R12, verbatim) ----------------
// Grid 512 blocks (linear). bid&7 = batch z (XCD L2 locality); (bid>>3)&31 =
// Q-tile (64 rows); bid>>8 = d-chunk (256 cols). 256 threads = 4 waves.
// s-block 64, 32 iters. Per iter:
//   QK: wave w computes S[qb*32..+32][sb*32..+32] (qb=w>>1, sb=w&1):
//       8 MFMA 32x32x16, 16 b128 reads. [bar]
//   issue K(kt+1) DMA (pre-swizzled src -> linear sK); V batch1 global->reg;
//   exp + rowsum + sP(64x64, swizzled). [bar: sP ready, vmcnt drained]
//   PV: wave w computes O[0:64][w*64..+64]: 16 MFMA, 8 sP reads, V from
//       blocked vT (global->reg, contiguous 1KB/wave-instr).
// LDS 40.75KB.
__global__ __launch_bounds__(256, 3) void attn_fused(
    const u16* __restrict__ qg, const u16* __restrict__ kg,
    const u16* __restrict__ vTg, u16* __restrict__ attg)
{
    __shared__ u16 sQ[64 * 128];     // 16 KB
    __shared__ u16 sK[64 * 128];     // 16 KB
    __shared__ u16 sP[64 * 64];      // 8 KB
    __shared__ float sRS[192];       // partials [4w][32] + inv [64]

    const int tid  = threadIdx.x;
    const int lane = tid & 63;
    const int w    = tid >> 6;       // 0..3
    const int l31  = lane & 31;
    const int hi   = lane >> 5;      // 0..1
    const int qb   = w >> 1;         // QK q-block
    const int sb   = w & 1;          // QK s-block

    const int  bid = blockIdx.x;
    const long z   = bid & 7;
    const int  r   = bid >> 3;
    const long q0  = (long)(r & 31) * 64;
    const long d0  = (long)(r >> 5) * 256;

    const u16* kbase0 = kg + z * (long)APF_T * APF_H;

    // prologue: stage Q + K tile 0 via DMA (pre-swizzled source, linear LDS)
    {
        const u16* qsrc = qg + (z * APF_T + q0) * APF_H;
#pragma unroll
        for (int rep = 0; rep < 4; ++rep) {
            const int c    = tid + rep * 256;     // 0..1023
            const int row  = c >> 4;
            const int col8 = (c & 15) * 8;
            load16_lds(qsrc + row * APF_H + (col8 ^ ((row & 15) << 3)), &sQ[c * 8]);
        }
#pragma unroll
        for (int rep = 0; rep < 4; ++rep) {
            const int c    = tid + rep * 256;     // 0..1023
            const int row  = c >> 4;
            const int col8 = (c & 15) * 8;
            load16_lds(kbase0 + row * APF_H + (col8 ^ ((row & 15) << 3)), &sK[c * 8]);
        }
    }
    __syncthreads();   // drains vmcnt: sQ, sK ready

    f32x16 oacc[2][2];
#pragma unroll
    for (int i = 0; i < 2; ++i)
#pragma unroll
        for (int j = 0; j < 2; ++j) oacc[i][j] = zero16();
    f32x16 rsacc = zero16();

    // blocked vT base for this wave: [z][dblk][s8][d&31][s&7]
    const long dblk0 = (d0 >> 5) + w * 2;
    const u16* vzb = vTg + z * 1048576L + dblk0 * 65536L + (long)l31 * 8;

    const int qrow = qb * 32 + l31;
    const int krow = sb * 32 + l31;
    const int pcol = sb * 32 + l31;

    for (int kt = 0; kt < APF_T / 64; ++kt) {
        // QK^T: S[qb*32..+32][sb*32..+32], h=128 -> 8 k-steps, 8 MFMA
        f32x16 sacc = zero16();
#pragma unroll
        for (int ks = 0; ks < 8; ++ks) {
            const int colk = ks * 16 + hi * 8;
            const short8 av = *(const short8*)&sQ[qrow * 128 + (colk ^ ((qrow & 15) << 3))];
            const short8 bv = *(const short8*)&sK[krow * 128 + (colk ^ ((krow & 15) << 3))];
            sacc = __builtin_amdgcn_mfma_f32_32x32x16_bf16(av, bv, sacc, 0, 0, 0);
        }
        __syncthreads();   // all waves done with sK(kt) and sP(kt-1)

        // issue next K tile DMA (completes by the sP barrier below)
        if (kt + 1 < APF_T / 64) {
            const u16* ksrc = kbase0 + (long)(kt + 1) * 64 * APF_H;
#pragma unroll
            for (int rep = 0; rep < 4; ++rep) {
                const int c    = tid + rep * 256;
                const int row  = c >> 4;
                const int col8 = (c & 15) * 8;
                load16_lds(ksrc + row * APF_H + (col8 ^ ((row & 15) << 3)), &sK[c * 8]);
            }
        }

        // V batch 1 prefetch (blocked layout: contiguous 1KB per instr)
        const long sbase = (long)kt * 8 + hi;
        short8 vf1[2][2];
#pragma unroll
        for (int dt = 0; dt < 2; ++dt)
#pragma unroll
            for (int ks = 0; ks < 2; ++ks)
                vf1[dt][ks] = *(const short8*)(vzb + dt * 65536L + (sbase + ks * 2) * 256);

        // exp + rowsum accum + P -> sP (swizzled; C-layout -> A-layout hop)
#pragma unroll
        for (int rg = 0; rg < 16; ++rg) {
            const float e = __expf(sacc[rg]);
            rsacc[rg] += e;
            const int prow = qb * 32 + (rg & 3) + 8 * (rg >> 2) + 4 * hi;
            sP[prow * 64 + (pcol ^ ((prow & 7) << 3))] = f2bf(e);
        }
        __syncthreads();   // sP visible; vmcnt drained (K DMA + vf complete)

        // PV batch 1 (ks 0..1): O[64][w*64..+64] += P @ V^T
#pragma unroll
        for (int ks = 0; ks < 2; ++ks) {
            const int colk = ks * 16 + hi * 8;
            short8 pa[2];
#pragma unroll
            for (int qt = 0; qt < 2; ++qt) {
                const int prow = qt * 32 + l31;
                pa[qt] = *(const short8*)&sP[prow * 64 + (colk ^ ((prow & 7) << 3))];
            }
#pragma unroll
            for (int dt = 0; dt < 2; ++dt)
#pragma unroll
                for (int qt = 0; qt < 2; ++qt)
                    oacc[qt][dt] = __builtin_amdgcn_mfma_f32_32x32x16_bf16(
                        pa[qt], vf1[dt][ks], oacc[qt][dt], 0, 0, 0);
        }

        // V batch 2 (ks 2..3)
        short8 vf2[2][2];
#pragma unroll
        for (int dt = 0; dt < 2; ++dt)
#pragma unroll
            for (int ks = 0; ks < 2; ++ks)
                vf2[dt][ks] = *(const short8*)(vzb + dt * 65536L + (sbase + (ks + 2) * 2) * 256);

        // PV batch 2 (ks 2..3)
#pragma unroll
        for (int ks = 0; ks < 2; ++ks) {
            const int colk = (ks + 2) * 16 + hi * 8;
            short8 pa[2];
#pragma unroll
            for (int qt = 0; qt < 2; ++qt) {
                const int prow = qt * 32 + l31;
                pa[qt] = *(const short8*)&sP[prow * 64 + (colk ^ ((prow & 7) << 3))];
            }
#pragma unroll
            for (int dt = 0; dt < 2; ++dt)
#pragma unroll
                for (int qt = 0; qt < 2; ++qt)
                    oacc[qt][dt] = __builtin_amdgcn_mfma_f32_32x32x16_bf16(
                        pa[qt], vf2[dt][ks], oacc[qt][dt], 0, 0, 0);
        }
    }

    // rowsum: reduce over the 32 s-cols (l31), publish per-wave partials
#pragma unroll
    for (int rg = 0; rg < 16; ++rg) {
        float s = rsacc[rg];
        s += __shfl_xor(s, 1);
        s += __shfl_xor(s, 2);
        s += __shfl_xor(s, 4);
        s += __shfl_xor(s, 8);
        s += __shfl_xor(s, 16);
        rsacc[rg] = s;
    }
    if (l31 == 0) {
#pragma unroll
        for (int rg = 0; rg < 16; ++rg) {
            const int row = (rg & 3) + 8 * (rg >> 2) + 4 * hi;   // 0..31
            sRS[w * 32 + row] = rsacc[rg];
        }
    }
    __syncthreads();
    if (tid < 64) {
        const int qb2 = tid >> 5, r2 = tid & 31;
        sRS[128 + tid] = 1.0f / (sRS[(qb2 * 2 + 0) * 32 + r2] +
                                 sRS[(qb2 * 2 + 1) * 32 + r2]);
    }
    __syncthreads();

    // store: 64 q rows x own 64 d cols
    const long rowg0 = z * APF_T + q0;
    const long colg0 = d0 + (long)w * 64;
#pragma unroll
    for (int qt = 0; qt < 2; ++qt)
#pragma unroll
        for (int rg = 0; rg < 16; ++rg) {
            const int row = qt * 32 + (rg & 3) + 8 * (rg >> 2) + 4 * hi;
            const float inv = sRS[128 + row];
#pragma unroll
            for (int dt = 0; dt < 2; ++dt)
                attg[(rowg0 + row) * APF_D + colg0 + dt * 32 + l31] =
                    f2bf(oacc[qt][dt][rg] * inv);
        }
}

extern "C" void kernel_launch(void* const* d_in, const int* in_sizes, int n_in,
                              void* d_out, int out_size, void* d_ws, size_t ws_size,
                              hipStream_t stream)
{
    (void)in_sizes; (void)n_in; (void)out_size; (void)ws_size;

    const float* x    = (const float*)d_in[0];
    const float* pred = (const float*)d_in[1];
    const float* Wq   = (const float*)d_in[2];
    const float* bq   = (const float*)d_in[3];
    const float* Wk   = (const float*)d_in[4];
    const float* bk   = (const float*)d_in[5];
    const float* Wv   = (const float*)d_in[6];
    const float* bv   = (const float*)d_in[7];
    const float* Wf   = (const float*)d_in[8];
    const float* bfu  = (const float*)d_in[9];

    // Workspace (u16), ~50 MB
    u16* wsp  = (u16*)d_ws;
    u16* qb   = wsp;                                   // [16384][128]
    u16* kbuf = qb   + (long)APF_M * APF_H;            // [16384][128]
    u16* vTb  = kbuf + (long)APF_M * APF_H;            // [8][16][256][32][8] blocked
    u16* attb = vTb  + (long)APF_M * APF_D;            // [16384][512]
    u16* WqT  = attb + (long)APF_M * APF_D;            // [128][512]
    u16* WkT  = WqT  + (long)APF_H * APF_D;            // [128][512]
    u16* WvT  = WkT  + (long)APF_H * APF_D;            // [512][512]
    u16* WfT  = WvT  + (long)APF_D * APF_D;            // [512][1024]

    const dim3 thr(256);

    // weights -> bf16 transposed (3.5MB, tiny)
    prep_w<<<dim3(3584), thr, 0, stream>>>(Wq, WqT, Wk, WkT, Wv, WvT, Wf, WfT);

    // q,k projections + vT in one 768-block launch (fp32 staged + cvt)
    mid_gemms<<<dim3(768), thr, 0, stream>>>(
        x, pred, WqT, WkT, WvT, bq, bk, bv, qb, kbuf, vTb);

    // fused attention: att = softmax(q k^T) v
    attn_fused<<<dim3(512), thr, 0, stream>>>(qb, kbuf, vTb, attb);

    // out = sigmoid([pred|att] @ Wf + bf) -> fp32 d_out
    fusion_gemm<<<dim3(4, 128), thr, 0, stream>>>(pred, attb, WfT, bfu,
                                                  (float*)d_out);
}